// Round 11
// baseline (669.309 us; speedup 1.0000x reference)
//
#include <hip/hip_runtime.h>
#include <hip/hip_bf16.h>
#include <cstdint>
#include <cstddef>

#define ALPHA 0.2f
#define MLP_SLOPE 0.01f

typedef short bf16x8 __attribute__((ext_vector_type(8)));
typedef float f32x4 __attribute__((ext_vector_type(4)));
typedef unsigned short ushort_t;

#define LGKM_FENCE() __asm__ __volatile__("s_waitcnt lgkmcnt(0)" ::: "memory")

__device__ __forceinline__ float lrelu(float x, float s) { return x > 0.f ? x : x * s; }
__device__ __forceinline__ ushort_t f2bf(float x) {
  __hip_bfloat16 h = __float2bfloat16(x);
  return *reinterpret_cast<ushort_t*>(&h);
}
__device__ __forceinline__ float bf2f(ushort_t u) {
  union { unsigned int i; float f; } v; v.i = ((unsigned int)u) << 16; return v.f;
}

// ---------------------------------------------------------------------------
// cast fp32 -> bf16, 4 elems/thread
// ---------------------------------------------------------------------------
__global__ __launch_bounds__(256) void tobf(
    const float* __restrict__ in, ushort_t* __restrict__ outp)
{
  int idx = blockIdx.x * 256 + threadIdx.x;
  float4 v = ((const float4*)in)[idx];
  ushort4 h;
  h.x = f2bf(v.x); h.y = f2bf(v.y); h.z = f2bf(v.z); h.w = f2bf(v.w);
  ((ushort4*)outp)[idx] = h;
}

// ---------------------------------------------------------------------------
__global__ __launch_bounds__(256) void zero_f(float* __restrict__ p)
{
  int idx = blockIdx.x * 256 + threadIdx.x;
  ((float4*)p)[idx] = make_float4(0.f, 0.f, 0.f, 0.f);
}

// ---------------------------------------------------------------------------
// Pack weights W[K,N] (batch via blockIdx.y) into MFMA B-fragment order.
// ---------------------------------------------------------------------------
__global__ __launch_bounds__(256) void pack_wt(
    const float* __restrict__ W, ushort_t* __restrict__ hi,
    ushort_t* __restrict__ lo, int K, int N)
{
  int gid = blockIdx.x * 256 + threadIdx.x;
  int lane = gid & 63;
  int kbc = K >> 5;
  int kblk = (gid >> 6) % kbc;
  int nblk = (gid >> 6) / kbc;
  size_t b = (size_t)blockIdx.y * K * N;
  int col = nblk * 16 + (lane & 15);
  int krow = kblk * 32 + (lane >> 4) * 8;
  ushort_t h[8] __attribute__((aligned(16)));
  ushort_t l[8] __attribute__((aligned(16)));
#pragma unroll
  for (int e = 0; e < 8; ++e) {
    float v = W[b + (size_t)(krow + e) * N + col];
    h[e] = f2bf(v);
    l[e] = f2bf(v - bf2f(h[e]));
  }
  *(uint4*)&hi[b + (size_t)gid * 8] = *(uint4*)h;
  if (lo) *(uint4*)&lo[b + (size_t)gid * 8] = *(uint4*)l;
}

// ---------------------------------------------------------------------------
// Fused h-GEMM (R9, frozen): h = x@Wg bf16; epilogue -> Bpack + s1/s2.
// ---------------------------------------------------------------------------
__global__ __launch_bounds__(256, 2) void gemm_h(
    const ushort_t* __restrict__ xb, const ushort_t* __restrict__ Wgp,
    const float* __restrict__ a1, const float* __restrict__ a2,
    ushort_t* __restrict__ Bpack, float* __restrict__ s1,
    float* __restrict__ s2)
{
  __shared__ ushort_t Ab[2][128][40];
  const int t = threadIdx.x;
  const int head = blockIdx.z;
  const int m0 = blockIdx.y * 128;
  const int n0 = blockIdx.x * 64;
  const int wave = t >> 6;
  const int wm = (wave & 1) * 64, wn = (wave >> 1) * 32;
  const int l16 = t & 15, quad = (t >> 4) & 3, l63 = t & 63;
  const int sr = t >> 1, sp = (t & 1) * 16;
  const ushort_t* arow_g = xb + (size_t)(m0 + sr) * 512 + sp;
  const ushort_t* bp = Wgp + (size_t)head * 256 * 512;
  const int nb0 = (n0 + wn) >> 4;

  f32x4 acc[4][2];
#pragma unroll
  for (int i = 0; i < 4; ++i)
#pragma unroll
    for (int j = 0; j < 2; ++j) acc[i][j] = (f32x4){0.f, 0.f, 0.f, 0.f};

  uint4 r0, r1;
  r0 = *(const uint4*)(arow_g);
  r1 = *(const uint4*)(arow_g + 8);
  *(uint4*)&Ab[0][sr][sp] = r0;
  *(uint4*)&Ab[0][sr][sp + 8] = r1;
  __syncthreads();

  for (int kb = 0; kb < 16; ++kb) {
    const int cur = kb & 1, nxt = cur ^ 1;
    if (kb < 15) {
      const ushort_t* p = arow_g + (kb + 1) * 32;
      r0 = *(const uint4*)p;
      r1 = *(const uint4*)(p + 8);
    }
    bf16x8 Bf[2];
#pragma unroll
    for (int nt = 0; nt < 2; ++nt)
      Bf[nt] = *(const bf16x8*)&bp[(((size_t)(nb0 + nt) * 16 + kb) * 64 + l63) * 8];
    bf16x8 Af[4];
#pragma unroll
    for (int mt = 0; mt < 4; ++mt)
      Af[mt] = *(const bf16x8*)&Ab[cur][wm + mt * 16 + l16][quad * 8];
#pragma unroll
    for (int mt = 0; mt < 4; ++mt)
#pragma unroll
      for (int nt = 0; nt < 2; ++nt)
        acc[mt][nt] = __builtin_amdgcn_mfma_f32_16x16x32_bf16(
            Af[mt], Bf[nt], acc[mt][nt], 0, 0, 0);
    if (kb < 15) {
      *(uint4*)&Ab[nxt][sr][sp] = r0;
      *(uint4*)&Ab[nxt][sr][sp + 8] = r1;
    }
    __syncthreads();
  }

#pragma unroll
  for (int mt = 0; mt < 4; ++mt)
#pragma unroll
    for (int nt = 0; nt < 2; ++nt)
#pragma unroll
      for (int rg = 0; rg < 4; ++rg) {
        int j = m0 + wm + mt * 16 + quad * 4 + rg;
        int c = n0 + wn + nt * 16 + l16;
        int kblk = j >> 5;
        int laneb = ((j >> 3) & 3) * 16 + (c & 15);
        int e = j & 7;
        Bpack[(((size_t)head * 256 + kblk) * 16 + (c >> 4)) * 512 + laneb * 8 + e] =
            f2bf(acc[mt][nt][rg]);
      }
  float a1v[2], a2v[2];
#pragma unroll
  for (int nt = 0; nt < 2; ++nt) {
    int c = n0 + wn + nt * 16 + l16;
    a1v[nt] = a1[head * 256 + c];
    a2v[nt] = a2[head * 256 + c];
  }
#pragma unroll
  for (int mt = 0; mt < 4; ++mt)
#pragma unroll
    for (int rg = 0; rg < 4; ++rg) {
      float p1 = acc[mt][0][rg] * a1v[0] + acc[mt][1][rg] * a1v[1];
      float p2 = acc[mt][0][rg] * a2v[0] + acc[mt][1][rg] * a2v[1];
      p1 += __shfl_xor(p1, 1); p2 += __shfl_xor(p2, 1);
      p1 += __shfl_xor(p1, 2); p2 += __shfl_xor(p2, 2);
      p1 += __shfl_xor(p1, 4); p2 += __shfl_xor(p2, 4);
      p1 += __shfl_xor(p1, 8); p2 += __shfl_xor(p2, 8);
      if (l16 == 0) {
        int row = m0 + wm + mt * 16 + quad * 4 + rg;
        atomicAdd(&s1[head * 8192 + row], p1);
        atomicAdd(&s2[head * 8192 + row], p2);
      }
    }
}

// ---------------------------------------------------------------------------
// Pipelined split-bf16 MLP GEMM (R9, frozen).
// ---------------------------------------------------------------------------
__global__ __launch_bounds__(256, 2) void gemm_mlp(
    const ushort_t* __restrict__ Ahi, const ushort_t* __restrict__ Alo,
    const ushort_t* __restrict__ Bph, const ushort_t* __restrict__ Bpl,
    const float* __restrict__ bias, float* __restrict__ Cf,
    ushort_t* __restrict__ Chi, ushort_t* __restrict__ Clo,
    int M, int N, int K, float slope)
{
  __shared__ ushort_t Ah[2][128][40], Al[2][128][40];
  const int kbc = K >> 5;
  const int t = threadIdx.x;
  const int m0 = blockIdx.y * 128;
  const int n0 = blockIdx.x * 64;
  const int wave = t >> 6;
  const int wm = (wave & 1) * 64, wn = (wave >> 1) * 32;
  const int l16 = t & 15, quad = (t >> 4) & 3, l63 = t & 63;
  const int sr = t >> 1, sp = (t & 1) * 16;
  const ushort_t* ah_g = Ahi + (size_t)(m0 + sr) * K + sp;
  const ushort_t* al_g = Alo + (size_t)(m0 + sr) * K + sp;
  const int nb0 = (n0 + wn) >> 4;

  f32x4 acc[4][2];
#pragma unroll
  for (int i = 0; i < 4; ++i)
#pragma unroll
    for (int j = 0; j < 2; ++j) acc[i][j] = (f32x4){0.f, 0.f, 0.f, 0.f};

  uint4 rh0, rh1, rl0, rl1;
  rh0 = *(const uint4*)(ah_g);
  rh1 = *(const uint4*)(ah_g + 8);
  rl0 = *(const uint4*)(al_g);
  rl1 = *(const uint4*)(al_g + 8);
  *(uint4*)&Ah[0][sr][sp] = rh0;
  *(uint4*)&Ah[0][sr][sp + 8] = rh1;
  *(uint4*)&Al[0][sr][sp] = rl0;
  *(uint4*)&Al[0][sr][sp + 8] = rl1;
  __syncthreads();

  for (int kb = 0; kb < kbc; ++kb) {
    const int cur = kb & 1, nxt = cur ^ 1;
    if (kb + 1 < kbc) {
      const ushort_t* ph = ah_g + (kb + 1) * 32;
      const ushort_t* plo = al_g + (kb + 1) * 32;
      rh0 = *(const uint4*)ph;
      rh1 = *(const uint4*)(ph + 8);
      rl0 = *(const uint4*)plo;
      rl1 = *(const uint4*)(plo + 8);
    }
    bf16x8 bh[2], bl[2];
#pragma unroll
    for (int nt = 0; nt < 2; ++nt) {
      size_t o = (((size_t)(nb0 + nt) * kbc + kb) * 64 + l63) * 8;
      bh[nt] = *(const bf16x8*)&Bph[o];
      bl[nt] = *(const bf16x8*)&Bpl[o];
    }
    bf16x8 afh[4], afl[4];
#pragma unroll
    for (int mt = 0; mt < 4; ++mt) {
      afh[mt] = *(const bf16x8*)&Ah[cur][wm + mt * 16 + l16][quad * 8];
      afl[mt] = *(const bf16x8*)&Al[cur][wm + mt * 16 + l16][quad * 8];
    }
#pragma unroll
    for (int mt = 0; mt < 4; ++mt)
#pragma unroll
      for (int nt = 0; nt < 2; ++nt) {
        acc[mt][nt] = __builtin_amdgcn_mfma_f32_16x16x32_bf16(afh[mt], bh[nt], acc[mt][nt], 0, 0, 0);
        acc[mt][nt] = __builtin_amdgcn_mfma_f32_16x16x32_bf16(afh[mt], bl[nt], acc[mt][nt], 0, 0, 0);
        acc[mt][nt] = __builtin_amdgcn_mfma_f32_16x16x32_bf16(afl[mt], bh[nt], acc[mt][nt], 0, 0, 0);
      }
    if (kb + 1 < kbc) {
      *(uint4*)&Ah[nxt][sr][sp] = rh0;
      *(uint4*)&Ah[nxt][sr][sp + 8] = rh1;
      *(uint4*)&Al[nxt][sr][sp] = rl0;
      *(uint4*)&Al[nxt][sr][sp + 8] = rl1;
    }
    __syncthreads();
  }

#pragma unroll
  for (int mt = 0; mt < 4; ++mt)
#pragma unroll
    for (int nt = 0; nt < 2; ++nt)
#pragma unroll
      for (int rg = 0; rg < 4; ++rg) {
        int m = m0 + wm + mt * 16 + quad * 4 + rg;
        int n = n0 + wn + nt * 16 + l16;
        float v = lrelu(acc[mt][nt][rg] + bias[n], slope);
        size_t o = (size_t)m * N + n;
        if (Cf) Cf[o] = v;
        if (Chi) {
          ushort_t h = f2bf(v);
          Chi[o] = h; Clo[o] = f2bf(v - bf2f(h));
        }
      }
}

// ---------------------------------------------------------------------------
// MFMA attention v9: PRODUCER-CONSUMER WAVE SPECIALIZATION. 768 threads:
// waves 0..7 = consumers (head, n-half, row-group; 128 rows x 256 cols,
// rowgroup pairs share Bf tiles -> L1 hits as in v8), waves 8..11 =
// producers streaming adj->exp->W into a 4-slot LDS ring. Sync via LDS
// flags (ready/done/pdone), lgkm fences, s_sleep polling. NO barrier in
// the K-loop: consumer MFMA runs back-to-back, producer VALU in its shadow,
// adj HBM latency absorbed by ring slack. Grid (64,4) = 256 blocks = 1/CU.
// ---------------------------------------------------------------------------
__global__ __launch_bounds__(768, 1) void attn_ps(
    const ushort_t* __restrict__ Bpack, const float* __restrict__ s1g,
    const float* __restrict__ s2g, const int* __restrict__ adj,
    ushort_t* __restrict__ pacc, float* __restrict__ pl)
{
  __shared__ ushort_t Wlds[4][2][8][64][8];   // 64 KB ring [slot][head][mt8][lane][8]
  __shared__ int ready[4];   // step+1 when slot fully generated
  __shared__ int done[4];    // cumulative consumer-wave completions
  __shared__ int pdone[4];   // cumulative producer-wave completions
  const int t = threadIdx.x;
  const int wave = t >> 6;
  const int i0 = blockIdx.x * 128;
  const int js = blockIdx.y;
  const int kbase = js * 2048;

  if (t < 4) { ready[t] = 0; done[t] = 0; pdone[t] = 0; }
  __syncthreads();

  if (wave >= 8) {
    // ======================= producers (4 waves) =======================
    const int tp = t - 512;          // 0..255
    const int wr = tp >> 1;          // row 0..127
    const int kqh = tp & 1;          // k-half: octets 2*kqh, 2*kqh+1
    const int gmt = wr >> 4;
    const int gl = wr & 15;
    const float s1v0 = s1g[i0 + wr];
    const float s1v1 = s1g[8192 + i0 + wr];
    const int* arow = adj + (size_t)(i0 + wr) * 8192;
    float rs0 = 0.f, rs1 = 0.f;

    for (int kt = 0; kt < 64; ++kt) {
      const int slot = kt & 3;
      const int kk = kbase + kt * 32 + kqh * 16;
      // issue this step's global loads FIRST; they fly during the poll
      int4 pa[4];
      float4 ps0[4], ps1[4];
#pragma unroll
      for (int i = 0; i < 4; ++i) {
        pa[i]  = *(const int4*)&arow[kk + i * 4];
        ps0[i] = *(const float4*)&s2g[kk + i * 4];
        ps1[i] = *(const float4*)&s2g[8192 + kk + i * 4];
      }
      // wait until consumers finished step kt-4 in this slot
      if (kt >= 4) {
        const int need = 8 * (kt >> 2);
        while (((volatile int*)done)[slot] < need) __builtin_amdgcn_s_sleep(1);
      }
      int am[16]; float sv0[16], sv1[16];
#pragma unroll
      for (int i = 0; i < 4; ++i) {
        am[i*4+0] = pa[i].x;  am[i*4+1] = pa[i].y;
        am[i*4+2] = pa[i].z;  am[i*4+3] = pa[i].w;
        sv0[i*4+0] = ps0[i].x; sv0[i*4+1] = ps0[i].y;
        sv0[i*4+2] = ps0[i].z; sv0[i*4+3] = ps0[i].w;
        sv1[i*4+0] = ps1[i].x; sv1[i*4+1] = ps1[i].y;
        sv1[i*4+2] = ps1[i].z; sv1[i*4+3] = ps1[i].w;
      }
#pragma unroll
      for (int q = 0; q < 2; ++q) {
        ushort_t w0[8] __attribute__((aligned(16)));
        ushort_t w1[8] __attribute__((aligned(16)));
#pragma unroll
        for (int e = 0; e < 8; ++e) {
          int i = q * 8 + e;
          float e0 = s1v0 + sv0[i];
          float e1 = s1v1 + sv1[i];
          e0 = fmaxf(e0, 0.f) + ALPHA * fminf(e0, 0.f);
          e1 = fmaxf(e1, 0.f) + ALPHA * fminf(e1, 0.f);
          float v0 = am[i] > 0 ? __expf(e0) : 0.f;
          float v1 = am[i] > 0 ? __expf(e1) : 0.f;
          rs0 += v0; rs1 += v1;
          w0[e] = f2bf(v0); w1[e] = f2bf(v1);
        }
        *(uint4*)&Wlds[slot][0][gmt][(kqh * 2 + q) * 16 + gl][0] = *(uint4*)w0;
        *(uint4*)&Wlds[slot][1][gmt][(kqh * 2 + q) * 16 + gl][0] = *(uint4*)w1;
      }
      LGKM_FENCE();   // this wave's W writes are in LDS
      if ((t & 63) == 0) {
        int old = atomicAdd(&pdone[slot], 1);
        if (old == 4 * (kt >> 2) + 3)            // last producer wave
          ((volatile int*)ready)[slot] = kt + 1;  // release
      }
    }
    // denominators: (wr,0)/(wr,1) are adjacent lanes
    rs0 += __shfl_xor(rs0, 1);
    rs1 += __shfl_xor(rs1, 1);
    if (kqh == 0) {
      pl[((size_t)js * 2 + 0) * 8192 + i0 + wr] = rs0;
      pl[((size_t)js * 2 + 1) * 8192 + i0 + wr] = rs1;
    }
  } else {
    // ======================= consumers (8 waves) =======================
    const int head = wave >> 2, nh = (wave >> 1) & 1, rg2 = wave & 1;
    const int l16 = t & 15, quad = (t >> 4) & 3, l63 = t & 63;
    f32x4 acc[4][8];
#pragma unroll
    for (int m = 0; m < 4; ++m)
#pragma unroll
      for (int n = 0; n < 8; ++n) acc[m][n] = (f32x4){0.f, 0.f, 0.f, 0.f};

    for (int kt = 0; kt < 64; ++kt) {
      const int slot = kt & 3;
      const int kblk = js * 64 + kt;
      const ushort_t* bb =
          Bpack + ((((size_t)head * 256 + kblk) * 16 + nh * 8) * 64 + l63) * 8;
      bf16x8 Bf[8];
#pragma unroll
      for (int nt = 0; nt < 8; ++nt)
        Bf[nt] = *(const bf16x8*)&bb[nt * 512];
      const int want = kt + 1;
      while (((volatile int*)ready)[slot] < want) __builtin_amdgcn_s_sleep(1);
      bf16x8 Af[4];
#pragma unroll
      for (int mt = 0; mt < 4; ++mt)
        Af[mt] = *(const bf16x8*)&Wlds[slot][head][rg2 * 4 + mt][l63][0];
      LGKM_FENCE();   // Af in registers; slot may be recycled now
      if ((t & 63) == 0) atomicAdd(&done[slot], 1);
#pragma unroll
      for (int mt = 0; mt < 4; ++mt)
#pragma unroll
        for (int nt = 0; nt < 8; ++nt)
          acc[mt][nt] = __builtin_amdgcn_mfma_f32_16x16x32_bf16(
              Af[mt], Bf[nt], acc[mt][nt], 0, 0, 0);
    }
    const int n0 = nh * 128;
#pragma unroll
    for (int mt = 0; mt < 4; ++mt)
#pragma unroll
      for (int nt = 0; nt < 8; ++nt)
#pragma unroll
        for (int rg = 0; rg < 4; ++rg) {
          int row = i0 + rg2 * 64 + mt * 16 + quad * 4 + rg;
          int col = n0 + nt * 16 + l16;
          pacc[(((size_t)js * 2 + head) * 8192 + row) * 256 + col] =
              f2bf(acc[mt][nt][rg]);
        }
  }
}

// ---------------------------------------------------------------------------
// Finalize (R9, frozen): emits embed directly as hi/lo bf16 split.
// ---------------------------------------------------------------------------
__global__ __launch_bounds__(256) void attn_finalize(
    const ushort_t* __restrict__ pacc, const float* __restrict__ pl,
    const float* __restrict__ bg, const float* __restrict__ llm,
    ushort_t* __restrict__ ehi, ushort_t* __restrict__ elo)
{
  __shared__ float red[8];
  const int r = blockIdx.x;
  const int t = threadIdx.x;
  const int wv = t >> 6, lane = t & 63;
#pragma unroll
  for (int half = 0; half < 2; ++half) {
    float lv = llm[(size_t)r * 512 + half * 256 + t];
    ushort_t h = f2bf(lv);
    ehi[(size_t)r * 768 + half * 256 + t] = h;
    elo[(size_t)r * 768 + half * 256 + t] = f2bf(lv - bf2f(h));
  }
  float o[2];
#pragma unroll
  for (int hh = 0; hh < 2; ++hh) {
    float num = 0.f, l = 0.f;
#pragma unroll
    for (int js = 0; js < 4; ++js) {
      num += bf2f(pacc[(((size_t)js * 2 + hh) * 8192 + r) * 256 + t]);
      l += pl[((size_t)js * 2 + hh) * 8192 + r];
    }
    o[hh] = lrelu(num / l, ALPHA);
  }
  float v0 = o[0] * o[0], v1 = o[1] * o[1];
  for (int off = 32; off > 0; off >>= 1) {
    v0 += __shfl_xor(v0, off);
    v1 += __shfl_xor(v1, off);
  }
  if (lane == 0) { red[wv] = v0; red[4 + wv] = v1; }
  __syncthreads();
  float n0 = fmaxf(sqrtf(red[0] + red[1] + red[2] + red[3]), 1e-12f);
  float n1 = fmaxf(sqrtf(red[4] + red[5] + red[6] + red[7]), 1e-12f);
  float val = 0.5f * (o[0] / n0 + bg[t] + o[1] / n1 + bg[256 + t]);
  ushort_t h = f2bf(val);
  ehi[(size_t)r * 768 + 512 + t] = h;
  elo[(size_t)r * 768 + 512 + t] = f2bf(val - bf2f(h));
}

// ---------------------------------------------------------------------------
__global__ __launch_bounds__(256) void pred_kernel(
    const float* __restrict__ z2, const int* __restrict__ ts,
    float* __restrict__ out, int E)
{
  const int gw = (blockIdx.x * 256 + threadIdx.x) >> 6;
  const int lane = threadIdx.x & 63;
  if (gw >= E) return;
  const int a = ts[gw * 2], b = ts[gw * 2 + 1];
  float4 va = ((const float4*)(z2 + (size_t)a * 256))[lane];
  float4 vb = ((const float4*)(z2 + (size_t)b * 256))[lane];
  float p = va.x * vb.x + va.y * vb.y + va.z * vb.z + va.w * vb.w;
  for (int off = 32; off > 0; off >>= 1) p += __shfl_xor(p, off);
  if (lane == 0) out[gw] = p;
}

// ---------------------------------------------------------------------------
extern "C" void kernel_launch(void* const* d_in, const int* in_sizes, int n_in,
                              void* d_out, int out_size, void* d_ws, size_t ws_size,
                              hipStream_t stream) {
  const float* x   = (const float*)d_in[0];
  const int*   adj = (const int*)d_in[1];
  const int*   ts  = (const int*)d_in[2];
  const float* llm = (const float*)d_in[3];
  const float* Wg  = (const float*)d_in[4];
  const float* a1  = (const float*)d_in[5];
  const float* a2  = (const float*)d_in[6];
  const float* bg  = (const float*)d_in[7];
  const float* W1  = (const float*)d_in[8];
  const float* b1  = (const float*)d_in[9];
  const float* W2  = (const float*)d_in[10];
  const float* b2  = (const float*)d_in[11];
  float* out = (float*)d_out;
  float* ws  = (float*)d_ws;
  const int E = in_sizes[2] / 2;

  // ---- workspace layout (float words) ----
  ushort_t* xb    = (ushort_t*)(ws + 0);            //  8192x512 bf16
  ushort_t* Wgp   = (ushort_t*)(ws + 2097152);      //  2x512x256
  ushort_t* W1ph  = (ushort_t*)(ws + 2228224);      //  768x512
  ushort_t* W1pl  = (ushort_t*)(ws + 2424832);
  ushort_t* W2ph  = (ushort_t*)(ws + 2621440);      //  512x256
  ushort_t* W2pl  = (ushort_t*)(ws + 2686976);
  ushort_t* Bpack = (ushort_t*)(ws + 2752512);      //  2x8192x256
  float*    s1    = ws + 4849664;                   //  2x8192
  float*    s2    = ws + 4866048;
  float*    pl    = ws + 4882432;                   //  8x8192
  ushort_t* pacc  = (ushort_t*)(ws + 4947968);      //  8x8192x256
  ushort_t* ehi   = (ushort_t*)(ws + 13336576);     //  8192x768
  ushort_t* elo   = (ushort_t*)(ws + 16482304);
  ushort_t* z1hi  = (ushort_t*)(ws + 19628032);     //  8192x512
  ushort_t* z1lo  = (ushort_t*)(ws + 21725184);
  float*    z2    = ws + 23822336;                  //  8192x256 f32

  // 1. prep: casts, weight packing, s-zero
  tobf<<<4096, 256, 0, stream>>>(x, xb);
  pack_wt<<<dim3(64, 2), 256, 0, stream>>>(Wg, Wgp, nullptr, 512, 256);
  pack_wt<<<dim3(192, 1), 256, 0, stream>>>(W1, W1ph, W1pl, 768, 512);
  pack_wt<<<dim3(64, 1), 256, 0, stream>>>(W2, W2ph, W2pl, 512, 256);
  zero_f<<<32, 256, 0, stream>>>(s1);   // covers s1 and s2 (contiguous)
  // 2. fused h-GEMM -> Bpack + s1/s2
  gemm_h<<<dim3(4, 64, 2), 256, 0, stream>>>(xb, Wgp, a1, a2, Bpack, s1, s2);
  // 3. MFMA attention partials (producer-consumer wave specialization)
  attn_ps<<<dim3(64, 4), 768, 0, stream>>>(Bpack, s1, s2, adj, pacc, pl);
  // 4. finalize -> embed as hi/lo split
  attn_finalize<<<8192, 256, 0, stream>>>(pacc, pl, bg, llm, ehi, elo);
  // 5. z1 = LR(embed @ W1 + b1) -> hi/lo
  gemm_mlp<<<dim3(8, 64), 256, 0, stream>>>(
      ehi, elo, W1ph, W1pl, b1, nullptr, z1hi, z1lo, 8192, 512, 768, MLP_SLOPE);
  // 6. z2 = LR(z1 @ W2 + b2) -> fp32
  gemm_mlp<<<dim3(4, 64), 256, 0, stream>>>(
      z1hi, z1lo, W2ph, W2pl, b2, z2, nullptr, nullptr, 8192, 256, 512, MLP_SLOPE);
  // 7. edge dots
  pred_kernel<<<(E * 64 + 255) / 256, 256, 0, stream>>>(z2, ts, out, E);
}